// Round 7
// baseline (83.881 us; speedup 1.0000x reference)
//
#include <hip/hip_runtime.h>

constexpr int Cc   = 224;            // channels
constexpr int Tt   = 224;            // time steps
constexpr int TT   = 32;             // time tile
constexpr int NT   = Tt / TT;        // 7
constexpr int LDW  = 36;             // words per LDS row (144 B) -> b128 bank-balanced
constexpr int ROWS = 236;            // row r <-> channel r-6; rows 0..5,230..235 zero halo
constexpr int BUFW = ROWS * LDW;     // 8496 words per buffer
constexpr int BDIM = 256;
constexpr int MSKOFF  = 2 * BUFW;            // pair-mask area (512 words)
constexpr int TAILOFF = 2 * BUFW + 512;      // tail-mask area (256 words)

__global__ __launch_bounds__(BDIM, 2)
void cgss_snn_kernel(const float* __restrict__ x,
                     const float* __restrict__ wp,
                     float* __restrict__ out)
{
    __shared__ float lds[2 * BUFW + 512 + 256];   // 71040 B -> 2 blocks/CU
    unsigned* msk  = reinterpret_cast<unsigned*>(&lds[MSKOFF]);
    unsigned* tmsk = reinterpret_cast<unsigned*>(&lds[TAILOFF]);

    const int tid = threadIdx.x;
    const int w   = tid >> 6;        // wave 0..3
    const int l   = tid & 63;
    const long long bofs = (long long)blockIdx.x * (Cc * Tt);
    const float* xb = x + bofs;
    float*       ob = out + bofs;

    // ---- zero halo rows (0..5, 230..235) in both buffers, once ----
    if (tid < 192) {
        int bufi = tid / 96;
        int q    = tid - 96 * bufi;
        int rr   = q >> 3;                       // 0..11
        int slot = q & 7;
        int row  = (rr < 6) ? rr : (224 + rr);   // 0..5, 230..235
        *reinterpret_cast<float4*>(&lds[bufi * BUFW + row * LDW + slot * 4]) =
            make_float4(0.f, 0.f, 0.f, 0.f);
    }

    // stage lane mapping: chunk i covers channels rowbase+8i (8 rows x 8 tq)
    const int srow = l >> 3;         // row within 8-row chunk
    const int stq  = l & 7;          // t-quad
    const int rowbase = 56 * w + srow;
    // pair-store lane mapping: 4 rows x 256B per instruction (full sectors)
    const int r2 = l >> 4;           // row in 4-row group
    const int o  = l & 15;           // 16B slot within 256B
    const int osel = o >> 3;         // which tile of the pair
    const int osh  = (o & 7) * 4;    // mask bit shift

    // ---- issue tile-0 loads (latency hidden under gaussian-kernel math) ----
    float4 vst[7];
#pragma unroll
    for (int i = 0; i < 7; ++i)
        vst[i] = *reinterpret_cast<const float4*>(
            xb + (rowbase + 8 * i) * Tt + 4 * stq);

    // ---- gaussian kernel (arithmetic identical to verified rounds 1-6) ----
    float kr[13];
    {
        float wv = wp[0];
        float wc = fminf(fmaxf(wv, 0.4f), 10.0f);
        float norm = 0.0f;
        const float step = 120.0f / 129.0f;
        for (int j = 0; j < 130; ++j) {
            float r = -60.0f + (float)j * step;
            float z = r / wc;
            norm += expf(-0.5f * z * z);
        }
        for (int i = 0; i < 13; ++i) {
            float r = (float)(i - 6);
            float z = r / wc;
            kr[i] = expf(-0.5f * z * z) / norm;
        }
    }

    // ---- write tile-0 into buf0; issue tile-1 loads ----
#pragma unroll
    for (int i = 0; i < 7; ++i)
        *reinterpret_cast<float4*>(
            &lds[(rowbase + 8 * i + 6) * LDW + 4 * stq]) = vst[i];
#pragma unroll
    for (int i = 0; i < 7; ++i)
        vst[i] = *reinterpret_cast<const float4*>(
            xb + (rowbase + 8 * i) * Tt + TT + 4 * stq);

    asm volatile("s_waitcnt lgkmcnt(0)" ::: "memory");
    __builtin_amdgcn_s_barrier();
    __builtin_amdgcn_sched_barrier(0);

    float mem = 0.f, rstv = 0.f;     // LIF state, carried across tiles
    unsigned mprev = 0;              // even-tile mask awaiting its pair
    int bufc = 0;

#pragma unroll 1
    for (int tile = 0; tile < NT; ++tile) {
        float* cur = &lds[bufc * BUFW];
        float* nxt = &lds[(bufc ^ 1) * BUFW];

        // ---- conv + LIF: 13 immediate-offset ds_read_b128 per quad ----
        unsigned m = 0;
        if (tid < Cc) {
            const float* base = cur + tid * LDW;   // rows tid..tid+12
#pragma unroll
            for (int tq = 0; tq < 8; ++tq) {
                float4 v[13];
#pragma unroll
                for (int k = 0; k < 13; ++k)
                    v[k] = *reinterpret_cast<const float4*>(base + k * LDW + 4 * tq);
                float4 acc = make_float4(0.f, 0.f, 0.f, 0.f);
#pragma unroll
                for (int k = 0; k < 13; ++k) {
                    float kk = kr[k];
                    acc.x += kk * v[k].x;  acc.y += kk * v[k].y;
                    acc.z += kk * v[k].z;  acc.w += kk * v[k].w;
                }
                const float* xv = (const float*)&v[6];   // center = own channel
                const float* av = (const float*)&acc;
#pragma unroll
                for (int s = 0; s < 4; ++s) {
                    float d  = xv[s] - av[s];
                    float rl = d > 0.0f ? d : 0.0f;
                    float I  = xv[s] - rl;               // I = x - relu(x - mean)
                    mem = 0.97f * mem + I - rstv;
                    bool sp = mem > 1.0f;
                    rstv = sp ? 1.0f : 0.0f;
                    m |= sp ? (1u << (4 * tq + s)) : 0u;
                }
            }
        }

        // ---- mask handling: pivot pairs through LDS at odd tiles ----
        if (tile & 1) {
            msk[2 * tid]     = mprev;
            msk[2 * tid + 1] = m;
        } else {
            mprev = m;
        }
        if (tile == NT - 1) tmsk[tid] = m;   // tail tile (even, NT=7)

        // ---- stage next tile: write regs (tile+1) into nxt, load tile+2 ----
        if (tile < NT - 1) {
#pragma unroll
            for (int i = 0; i < 7; ++i)
                *reinterpret_cast<float4*>(
                    &nxt[(rowbase + 8 * i + 6) * LDW + 4 * stq]) = vst[i];
        }
        if (tile < NT - 2) {
            const float* src = xb + (tile + 2) * TT + 4 * stq;
#pragma unroll
            for (int i = 0; i < 7; ++i)
                vst[i] = *reinterpret_cast<const float4*>(
                    src + (rowbase + 8 * i) * Tt);
        }

        // one barrier per tile (also protects msk/tmsk visibility)
        asm volatile("s_waitcnt lgkmcnt(0)" ::: "memory");
        __builtin_amdgcn_s_barrier();
        __builtin_amdgcn_sched_barrier(0);

        // ---- pair store: full 256B-aligned sectors, overlapped with compute ----
        if (tile & 1) {
            const int p = tile >> 1;             // pair index 0..2
#pragma unroll
            for (int j = 0; j < 14; ++j) {
                int cr = 56 * w + 4 * j + r2;
                unsigned mk = msk[2 * cr + osel];
                unsigned rb = mk >> osh;
                float4 s4;
                s4.x = (rb & 1u) ? 1.0f : 0.0f;
                s4.y = (rb & 2u) ? 1.0f : 0.0f;
                s4.z = (rb & 4u) ? 1.0f : 0.0f;
                s4.w = (rb & 8u) ? 1.0f : 0.0f;
                *reinterpret_cast<float4*>(
                    &ob[(long long)cr * Tt + 64 * p + 4 * o]) = s4;
            }
        }
        bufc ^= 1;
    }

    // ---- tail store (tile 6, t0=192): 8 rows x 128B per instruction ----
#pragma unroll
    for (int i = 0; i < 7; ++i) {
        int cr = rowbase + 8 * i;
        unsigned mk = tmsk[cr];
        unsigned rb = mk >> (4 * stq);
        float4 s4;
        s4.x = (rb & 1u) ? 1.0f : 0.0f;
        s4.y = (rb & 2u) ? 1.0f : 0.0f;
        s4.z = (rb & 4u) ? 1.0f : 0.0f;
        s4.w = (rb & 8u) ? 1.0f : 0.0f;
        *reinterpret_cast<float4*>(&ob[(long long)cr * Tt + 192 + 4 * stq]) = s4;
    }
}

extern "C" void kernel_launch(void* const* d_in, const int* in_sizes, int n_in,
                              void* d_out, int out_size, void* d_ws, size_t ws_size,
                              hipStream_t stream)
{
    const float* x  = (const float*)d_in[0];
    const float* w  = (const float*)d_in[1];
    float* out      = (float*)d_out;
    const int B = in_sizes[0] / (Cc * Tt);   // 512
    cgss_snn_kernel<<<B, BDIM, 0, stream>>>(x, w, out);
}

// Round 8
// 83.745 us; speedup vs baseline: 1.0016x; 1.0016x over previous
//
#include <hip/hip_runtime.h>

constexpr int Cc   = 224;            // channels
constexpr int Tt   = 224;            // time steps
constexpr int TT   = 32;             // time tile
constexpr int NT   = Tt / TT;        // 7
constexpr int LDW  = 36;             // words per LDS row (144 B) -> b128 bank-balanced
constexpr int ROWS = 236;            // row r <-> channel r-6; rows 0..5,230..235 zero halo
constexpr int BUFW = ROWS * LDW;     // 8496 words per buffer
constexpr int BDIM = 256;

__global__ __launch_bounds__(BDIM, 2)
void cgss_snn_kernel(const float* __restrict__ x,
                     const float* __restrict__ wp,
                     float* __restrict__ out)
{
    __shared__ float lds[2 * BUFW];  // 67968 B -> 2 blocks/CU
    // mask pivot area overlays buf1 (dead after the tile-5 end barrier)
    unsigned* msk = reinterpret_cast<unsigned*>(&lds[BUFW]);   // msk[c*8 + tile]

    const int tid = threadIdx.x;
    const int w   = tid >> 6;        // wave 0..3
    const int l   = tid & 63;
    const long long bofs = (long long)blockIdx.x * (Cc * Tt);
    const float* xb = x + bofs;
    float*       ob = out + bofs;

    // ---- zero halo rows (0..5, 230..235) in both buffers, once ----
    if (tid < 192) {
        int bufi = tid / 96;
        int q    = tid - 96 * bufi;
        int rr   = q >> 3;                       // 0..11
        int slot = q & 7;
        int row  = (rr < 6) ? rr : (224 + rr);   // 0..5, 230..235
        *reinterpret_cast<float4*>(&lds[bufi * BUFW + row * LDW + slot * 4]) =
            make_float4(0.f, 0.f, 0.f, 0.f);
    }

    // stage lane mapping: chunk i covers channels rowbase+8i (8 rows x 8 tq)
    const int srow = l >> 3;         // row within 8-row chunk
    const int stq  = l & 7;          // t-quad
    const int rowbase = 56 * w + srow;

    // ---- issue tile-0 loads (latency hidden under gaussian-kernel math) ----
    float4 vst[7];
#pragma unroll
    for (int i = 0; i < 7; ++i)
        vst[i] = *reinterpret_cast<const float4*>(
            xb + (rowbase + 8 * i) * Tt + 4 * stq);

    // ---- gaussian kernel (arithmetic identical to verified rounds 1-7) ----
    float kr[13];
    {
        float wv = wp[0];
        float wc = fminf(fmaxf(wv, 0.4f), 10.0f);
        float norm = 0.0f;
        const float step = 120.0f / 129.0f;
        for (int j = 0; j < 130; ++j) {
            float r = -60.0f + (float)j * step;
            float z = r / wc;
            norm += expf(-0.5f * z * z);
        }
        for (int i = 0; i < 13; ++i) {
            float r = (float)(i - 6);
            float z = r / wc;
            kr[i] = expf(-0.5f * z * z) / norm;
        }
    }

    // ---- write tile-0 into buf0; issue tile-1 loads ----
#pragma unroll
    for (int i = 0; i < 7; ++i)
        *reinterpret_cast<float4*>(
            &lds[(rowbase + 8 * i + 6) * LDW + 4 * stq]) = vst[i];
#pragma unroll
    for (int i = 0; i < 7; ++i)
        vst[i] = *reinterpret_cast<const float4*>(
            xb + (rowbase + 8 * i) * Tt + TT + 4 * stq);

    asm volatile("s_waitcnt lgkmcnt(0)" ::: "memory");
    __builtin_amdgcn_s_barrier();
    __builtin_amdgcn_sched_barrier(0);

    float mem = 0.f, rstv = 0.f;     // LIF state, carried across tiles
    // spike masks: one 32-bit word per tile, static shift register
    unsigned r0 = 0, r1 = 0, r2 = 0, r3 = 0, r4 = 0, r5 = 0, r6 = 0;
    int bufc = 0;

#pragma unroll 1
    for (int tile = 0; tile < NT; ++tile) {
        float* cur = &lds[bufc * BUFW];
        float* nxt = &lds[(bufc ^ 1) * BUFW];

        // ---- conv + LIF: 13 immediate-offset ds_read_b128 per quad ----
        unsigned m = 0;
        if (tid < Cc) {
            const float* base = cur + tid * LDW;   // rows tid..tid+12
#pragma unroll
            for (int tq = 0; tq < 8; ++tq) {
                float4 v[13];
#pragma unroll
                for (int k = 0; k < 13; ++k)
                    v[k] = *reinterpret_cast<const float4*>(base + k * LDW + 4 * tq);
                float4 acc = make_float4(0.f, 0.f, 0.f, 0.f);
#pragma unroll
                for (int k = 0; k < 13; ++k) {
                    float kk = kr[k];
                    acc.x += kk * v[k].x;  acc.y += kk * v[k].y;
                    acc.z += kk * v[k].z;  acc.w += kk * v[k].w;
                }
                const float* xv = (const float*)&v[6];   // center = own channel
                const float* av = (const float*)&acc;
#pragma unroll
                for (int s = 0; s < 4; ++s) {
                    float d  = xv[s] - av[s];
                    float rl = d > 0.0f ? d : 0.0f;
                    float I  = xv[s] - rl;               // I = x - relu(x - mean)
                    mem = 0.97f * mem + I - rstv;
                    bool sp = mem > 1.0f;
                    rstv = sp ? 1.0f : 0.0f;
                    m |= sp ? (1u << (4 * tq + s)) : 0u;
                }
            }
        }
        // static shift register: after 7 tiles r0..r6 = tiles 0..6
        r0 = r1; r1 = r2; r2 = r3; r3 = r4; r4 = r5; r5 = r6; r6 = m;

        // ---- stage next tile: write regs (tile+1) into nxt, load tile+2 ----
        if (tile < NT - 1) {
#pragma unroll
            for (int i = 0; i < 7; ++i)
                *reinterpret_cast<float4*>(
                    &nxt[(rowbase + 8 * i + 6) * LDW + 4 * stq]) = vst[i];
        }
        if (tile < NT - 2) {
            const float* src = xb + (tile + 2) * TT + 4 * stq;
#pragma unroll
            for (int i = 0; i < 7; ++i)
                vst[i] = *reinterpret_cast<const float4*>(
                    src + (rowbase + 8 * i) * Tt);
        }

        if (tile < NT - 1) {
            asm volatile("s_waitcnt lgkmcnt(0)" ::: "memory");
            __builtin_amdgcn_s_barrier();       // double-buffer hazard guard
            __builtin_amdgcn_sched_barrier(0);
        }
        bufc ^= 1;
    }

    // ---- pivot masks through buf1 (free since the tile-5 end barrier) ----
    if (tid < Cc) {
        unsigned* mr = msk + tid * 8;
        mr[0] = r0; mr[1] = r1; mr[2] = r2; mr[3] = r3;
        mr[4] = r4; mr[5] = r5; mr[6] = r6;
    }
    asm volatile("s_waitcnt lgkmcnt(0)" ::: "memory");
    __builtin_amdgcn_s_barrier();               // cross-wave mask visibility
    __builtin_amdgcn_sched_barrier(0);

    // ---- sector-perfect burst store ----
    // Each 8-row group is flat 7168B = 28 aligned 256B sectors; each instr
    // writes 1024B = 4 FULL sectors -> zero write amplification by layout.
#pragma unroll 1
    for (int g = 0; g < 7; ++g) {
        const int rg = 56 * w + 8 * g;               // first channel of group
        float* gb = ob + (long long)rg * Tt;         // 7168B-aligned base
        const unsigned* mg = msk + rg * 8;
#pragma unroll
        for (int k = 0; k < 7; ++k) {
            int fq  = 64 * k + l;                    // 4-float chunk index in group
            int r   = fq / 56;                       // row within group (0..7)
            int rem = fq - 56 * r;                   // 4-float chunk within row
            unsigned mk = mg[r * 8 + (rem >> 3)];    // tile word (broadcast x8 lanes)
            unsigned rb = mk >> ((rem & 7) * 4);
            float4 s4;
            s4.x = (rb & 1u) ? 1.0f : 0.0f;
            s4.y = (rb & 2u) ? 1.0f : 0.0f;
            s4.z = (rb & 4u) ? 1.0f : 0.0f;
            s4.w = (rb & 8u) ? 1.0f : 0.0f;
            *reinterpret_cast<float4*>(gb + 4 * fq) = s4;
        }
    }
}

extern "C" void kernel_launch(void* const* d_in, const int* in_sizes, int n_in,
                              void* d_out, int out_size, void* d_ws, size_t ws_size,
                              hipStream_t stream)
{
    const float* x  = (const float*)d_in[0];
    const float* w  = (const float*)d_in[1];
    float* out      = (float*)d_out;
    const int B = in_sizes[0] / (Cc * Tt);   // 512
    cgss_snn_kernel<<<B, BDIM, 0, stream>>>(x, w, out);
}